// Round 7
// baseline (7682.111 us; speedup 1.0000x reference)
//
#include <hip/hip_runtime.h>

// InputAttnEncoder round 7: kill scratch rings + deepen MLP.
// r4-r6 invariant 29us/step traced to (1) bufA[(kc+4)%5] runtime index under
// partial unroll -> scratch array -> serialized scratch round-trips per MFMA,
// (2) depth-2 rings exposing ~250cy L2 latency per 4-MFMA group.
// Fix: FULL unroll (all ring indices compile-time), ring-5/3/3, cross-phase
// load hoisting (fills issue before barriers), attn1 j=256 column moved from
// a wave-0-only MFMA tile to an all-wave VALU dot (LDS w16 table).
// 32 blocks x 512 threads (8 waves), gates/c in registers, attn2 LDS-pinned.

#define Bb 512
#define Tt 256
#define Ff 128
#define Hh 256

typedef unsigned short ushort_t;
typedef short s16x8 __attribute__((ext_vector_type(8)));
typedef float f32x4 __attribute__((ext_vector_type(4)));

#define A1_NK 20
#define A2_NK 9
#define IH_NK 4
#define HH_NK 8
#define CH_A1 0
#define CH_A2 21760
#define CH_IH 26368
#define CH_HH 42752
#define CH_TOTAL 75520

#define ZP 648    // z row pitch (ushort): [x 0..127 | h 128..383 | c 384..639]
#define AP 296    // attn score row pitch (K padded 257->288, pads zero)
#define XIP 136   // xi row pitch

__device__ inline ushort_t f2b(float f) {
    unsigned u = __float_as_uint(f);
    unsigned r = (u + 0x7fffu + ((u >> 16) & 1u)) >> 16;  // RNE
    return (ushort_t)r;
}
__device__ inline float b2f(ushort_t u) {
    return __uint_as_float(((unsigned)u) << 16);
}
__device__ inline float fast_sig(float x) { return 1.f / (1.f + __expf(-x)); }
__device__ inline float fast_tanh(float x) {
    float cx = fminf(fmaxf(x, -15.f), 15.f);
    float e = __expf(2.f * cx);
    return (e - 1.f) / (e + 1.f);
}

__global__ void conv_kernel(const float* __restrict__ a1,  // [257][640]
                            const float* __restrict__ a2,  // [128][257]
                            const float* __restrict__ ih,  // [1024][128]
                            const float* __restrict__ hh,  // [1024][256]
                            ushort_t* __restrict__ ws) {
    int idx = blockIdx.x * 256 + threadIdx.x;
    if (idx >= CH_TOTAL) return;
    int lane = idx & 63;
    int jo = lane & 15;
    int ko = (lane >> 4) * 8;
    float v[8];
    if (idx < CH_A2) {
        int cix = idx >> 6;
        int tile = cix / A1_NK, kc = cix % A1_NK;
        int j = tile * 16 + jo, k = kc * 32 + ko;
        #pragma unroll
        for (int e = 0; e < 8; ++e) v[e] = (j < 257) ? a1[j * 640 + k + e] : 0.f;
    } else if (idx < CH_IH) {
        int cix = (idx - CH_A2) >> 6;
        int tile = cix / A2_NK, kc = cix % A2_NK;
        int j = tile * 16 + jo, k = kc * 32 + ko;
        #pragma unroll
        for (int e = 0; e < 8; ++e) v[e] = (k + e < 257) ? a2[j * 257 + k + e] : 0.f;
    } else if (idx < CH_HH) {
        int cix = (idx - CH_IH) >> 6;
        int tile = cix / IH_NK, kc = cix % IH_NK;
        int j = tile * 16 + jo, k = kc * 32 + ko;
        #pragma unroll
        for (int e = 0; e < 8; ++e) v[e] = ih[j * 128 + k + e];
    } else {
        int cix = (idx - CH_HH) >> 6;
        int tile = cix / HH_NK, kc = cix % HH_NK;
        int j = tile * 16 + jo, k = kc * 32 + ko;
        #pragma unroll
        for (int e = 0; e < 8; ++e) v[e] = hh[j * 256 + k + e];
    }
    union { s16x8 v8; ushort_t u[8]; } o;
    #pragma unroll
    for (int e = 0; e < 8; ++e) o.u[e] = f2b(v[e]);
    ((s16x8*)ws)[idx] = o.v8;
}

__global__ __launch_bounds__(512, 1) void lstm_mfma(
    const float* __restrict__ X,    // [512][256][128]
    const float* __restrict__ b1,   // [257]
    const float* __restrict__ b2,   // [128]
    const float* __restrict__ bih,  // [1024]
    const float* __restrict__ bhh,  // [1024]
    const ushort_t* __restrict__ wsw,
    float* __restrict__ out)        // hs [512][256][256] then cs
{
    __shared__ s16x8    a2w[8 * A2_NK * 64];   // 73,728 B: attn2 weights pinned
    __shared__ ushort_t z_bf[16][ZP];          // 20,736 B
    __shared__ ushort_t a_bf[16][AP];          //  9,472 B
    __shared__ ushort_t xi_bf[16][XIP];        //  4,352 B
    __shared__ ushort_t w16[640];              //  1,280 B: attn1 j=256 weights

    const int tid = threadIdx.x;
    const int w   = tid >> 6;       // wave 0..7
    const int l   = tid & 63;
    const int lj  = l & 15;
    const int lr4 = (l >> 4) * 4;
    const int lk8 = (l >> 4) * 8;
    const int b0  = blockIdx.x * 16;

    const s16x8* __restrict__ W8 = (const s16x8*)wsw;

    // ---------------- gate biases ----------------
    float bgq[8];
    #pragma unroll
    for (int u = 0; u < 8; ++u) {
        int n = (u & 3) * 16 + (u >> 2) * 8 + w;   // gate tile
        int j = n * 16 + lj;
        bgq[u] = bih[j] + bhh[j];
    }

    // ---------------- pinned weights: attn2 into LDS ----------------
    for (int i = tid; i < 8 * A2_NK * 64; i += 512) a2w[i] = W8[CH_A2 + i];
    // attn1 tile-16 (j=256) weights into w16[640]
    if (tid < 80) {
        int kc = tid >> 2, sub = tid & 3;
        *(s16x8*)&w16[kc * 32 + sub * 8] = W8[CH_A1 + (16 * A1_NK + kc) * 64 + sub * 16];
    }

    // ---------------- biases ----------------
    float bA1_0 = b1[16 * w + lj];
    float bA1_1 = b1[128 + 16 * w + lj];
    float b256  = b1[256];
    float bA2   = b2[16 * w + lj];

    f32x4 agate[8];
    float c_reg[8];
    #pragma unroll
    for (int u = 0; u < 8; ++u) c_reg[u] = 0.f;

    // stream ring buffers (all statically indexed via full unroll)
    s16x8 bufA[5][2];
    s16x8 bufH[3][4];
    s16x8 bufI[3][4];

    // ---------------- LDS init ----------------
    {
        s16x8 zz = {0, 0, 0, 0, 0, 0, 0, 0};
        #pragma unroll
        for (int rep = 0; rep < 2; ++rep) {
            int i = tid + rep * 512;
            int r = i >> 6, c = (i & 63) * 8;
            *(s16x8*)&z_bf[r][128 + c] = zz;
        }
        for (int i = tid; i < 592; i += 512) {   // a_bf incl pads
            int r = i / 37, c = (i - r * 37) * 8;
            *(s16x8*)&a_bf[r][c] = zz;
        }
    }
    if (tid < 256) {  // x_0
        int r = tid >> 4, c = (tid & 15) * 8;
        float4 x0 = *(const float4*)&X[((size_t)(b0 + r) * Tt) * Ff + c];
        float4 x1 = *(const float4*)&X[((size_t)(b0 + r) * Tt) * Ff + c + 4];
        s16x8 v;
        v[0] = (short)f2b(x0.x); v[1] = (short)f2b(x0.y);
        v[2] = (short)f2b(x0.z); v[3] = (short)f2b(x0.w);
        v[4] = (short)f2b(x1.x); v[5] = (short)f2b(x1.y);
        v[6] = (short)f2b(x1.z); v[7] = (short)f2b(x1.w);
        *(s16x8*)&z_bf[r][c] = v;
    }

    // prologue: fill A1 ring (kc 0..4) before the init barrier
    #pragma unroll
    for (int kc = 0; kc < 5; ++kc) {
        bufA[kc][0] = W8[CH_A1 + (w * A1_NK + kc) * 64 + l];
        bufA[kc][1] = W8[CH_A1 + ((8 + w) * A1_NK + kc) * 64 + l];
    }
    __syncthreads();

    float* __restrict__ hs = out;
    float* __restrict__ cs = out + (size_t)Bb * Tt * Hh;

    float4 xp0, xp1;

    for (int t = 0; t < Tt; ++t) {
        // ===== Phase A: attn1 (2 tiles/wave, ring-5) + col-256 VALU dot =====
        {
            const s16x8* Wa = W8 + CH_A1;
            f32x4 acc0 = {0.f, 0.f, 0.f, 0.f};
            f32x4 acc1 = {0.f, 0.f, 0.f, 0.f};
            #pragma unroll
            for (int kc = 0; kc < A1_NK; ++kc) {
                s16x8 a = *(const s16x8*)&z_bf[lj][kc * 32 + lk8];
                acc0 = __builtin_amdgcn_mfma_f32_16x16x32_bf16(a, bufA[kc % 5][0], acc0, 0, 0, 0);
                acc1 = __builtin_amdgcn_mfma_f32_16x16x32_bf16(a, bufA[kc % 5][1], acc1, 0, 0, 0);
                if (kc + 5 < A1_NK) {
                    bufA[kc % 5][0] = Wa[(w * A1_NK + kc + 5) * 64 + l];
                    bufA[kc % 5][1] = Wa[((8 + w) * A1_NK + kc + 5) * 64 + l];
                }
            }
            // Whh ring fill (groups 0..2) — hide under barrier + tanh tail
            #pragma unroll
            for (int g = 0; g < 3; ++g) {
                #pragma unroll
                for (int j2 = 0; j2 < 4; ++j2) {
                    int u = (g & 1) * 4 + j2;
                    int n = (u & 3) * 16 + (u >> 2) * 8 + w;
                    bufH[g][j2] = W8[CH_HH + (n * HH_NK + (g >> 1)) * 64 + l];
                }
            }
            int j0 = 16 * w + lj;
            #pragma unroll
            for (int q = 0; q < 4; ++q) {
                a_bf[lr4 + q][j0]       = f2b(fast_tanh(acc0[q] + bA1_0));
                a_bf[lr4 + q][128 + j0] = f2b(fast_tanh(acc1[q] + bA1_1));
            }
            // col 256: all-wave VALU dot for rows 2w, 2w+1
            {
                int r0 = 2 * w, r1 = 2 * w + 1;
                float d0 = 0.f, d1 = 0.f;
                #pragma unroll
                for (int jj = 0; jj < 10; ++jj) {
                    float wv = b2f(w16[l + 64 * jj]);
                    d0 = fmaf(b2f(z_bf[r0][l + 64 * jj]), wv, d0);
                    d1 = fmaf(b2f(z_bf[r1][l + 64 * jj]), wv, d1);
                }
                #pragma unroll
                for (int m = 1; m < 64; m <<= 1) {
                    d0 += __shfl_xor(d0, m, 64);
                    d1 += __shfl_xor(d1, m, 64);
                }
                if (l == 0) {
                    a_bf[r0][256] = f2b(fast_tanh(d0 + b256));
                    a_bf[r1][256] = f2b(fast_tanh(d1 + b256));
                }
            }
        }
        __syncthreads();  // ---- a_bf ready ----

        // ===== Phase B: x prefetch + attn2 (LDS) + Whh (ring-3) =====
        if (tid < 256 && t + 1 < Tt) {
            const float* xs = &X[((size_t)(b0 + (tid >> 4)) * Tt + (t + 1)) * Ff + (tid & 15) * 8];
            xp0 = *(const float4*)xs;
            xp1 = *(const float4*)(xs + 4);
        }
        #pragma unroll
        for (int u = 0; u < 8; ++u)
            agate[u] = (f32x4){bgq[u], bgq[u], bgq[u], bgq[u]};
        {   // attn2 — LDS-pinned B; runs while Whh groups 0-2 are in flight
            f32x4 acc = {0.f, 0.f, 0.f, 0.f};
            #pragma unroll
            for (int kc = 0; kc < A2_NK; ++kc) {
                s16x8 a = *(const s16x8*)&a_bf[lj][kc * 32 + lk8];
                s16x8 b = a2w[(w * A2_NK + kc) * 64 + l];
                acc = __builtin_amdgcn_mfma_f32_16x16x32_bf16(a, b, acc, 0, 0, 0);
            }
            int j = 16 * w + lj;
            #pragma unroll
            for (int q = 0; q < 4; ++q) {
                int r = lr4 + q;
                float xi = (acc[q] + bA2) * b2f(z_bf[r][j]);
                xi_bf[r][j] = f2b(xi);
            }
        }
        {   // Whh: 16 groups of 4 tiles, ring-3 (12 loads in flight)
            s16x8 ah;
            #pragma unroll
            for (int g = 0; g < 16; ++g) {
                const int kc = g >> 1, half = g & 1, slot = g % 3;
                if (half == 0)
                    ah = *(const s16x8*)&z_bf[lj][128 + kc * 32 + lk8];
                #pragma unroll
                for (int j2 = 0; j2 < 4; ++j2)
                    agate[half * 4 + j2] = __builtin_amdgcn_mfma_f32_16x16x32_bf16(
                        ah, bufH[slot][j2], agate[half * 4 + j2], 0, 0, 0);
                if (g + 3 < 16) {
                    const int gg = g + 3, kn = gg >> 1, hn = gg & 1;
                    #pragma unroll
                    for (int j2 = 0; j2 < 4; ++j2) {
                        int u = hn * 4 + j2;
                        int n = (u & 3) * 16 + (u >> 2) * 8 + w;
                        bufH[slot][j2] = W8[CH_HH + (n * HH_NK + kn) * 64 + l];
                    }
                }
            }
        }
        // Wih ring fill (groups 0..2) — hide under the xi barrier
        #pragma unroll
        for (int g = 0; g < 3; ++g) {
            #pragma unroll
            for (int j2 = 0; j2 < 4; ++j2) {
                int u = (g & 1) * 4 + j2;
                int n = (u & 3) * 16 + (u >> 2) * 8 + w;
                bufI[g][j2] = W8[CH_IH + (n * IH_NK + (g >> 1)) * 64 + l];
            }
        }
        __syncthreads();  // ---- xi ready ----

        // ===== Phase C: Wih (ring-3) + pointwise + state/output writes =====
        {
            s16x8 ax;
            #pragma unroll
            for (int g = 0; g < 8; ++g) {
                const int kc = g >> 1, half = g & 1, slot = g % 3;
                if (half == 0)
                    ax = *(const s16x8*)&xi_bf[lj][kc * 32 + lk8];
                #pragma unroll
                for (int j2 = 0; j2 < 4; ++j2)
                    agate[half * 4 + j2] = __builtin_amdgcn_mfma_f32_16x16x32_bf16(
                        ax, bufI[slot][j2], agate[half * 4 + j2], 0, 0, 0);
                if (g + 3 < 8) {
                    const int gg = g + 3, kn = gg >> 1, hn = gg & 1;
                    #pragma unroll
                    for (int j2 = 0; j2 < 4; ++j2) {
                        int u = hn * 4 + j2;
                        int n = (u & 3) * 16 + (u >> 2) * 8 + w;
                        bufI[slot][j2] = W8[CH_IH + (n * IH_NK + kn) * 64 + l];
                    }
                }
            }
            #pragma unroll
            for (int q = 0; q < 2; ++q) {
                int d = 128 * q + 16 * w + lj;
                #pragma unroll
                for (int qq = 0; qq < 4; ++qq) {
                    int r = lr4 + qq;
                    float gi = agate[q * 4 + 0][qq];
                    float gf = agate[q * 4 + 1][qq];
                    float gg = agate[q * 4 + 2][qq];
                    float go = agate[q * 4 + 3][qq];
                    float ig = fast_sig(gi);
                    float fg = fast_sig(gf);
                    float g_g = fast_tanh(gg);
                    float og = fast_sig(go);
                    float cn = fmaf(fg, c_reg[q * 4 + qq], ig * g_g);
                    float hn = og * fast_tanh(cn);
                    c_reg[q * 4 + qq] = cn;
                    z_bf[r][128 + d] = f2b(hn);
                    z_bf[r][384 + d] = f2b(cn);
                    size_t oi = ((size_t)(b0 + r) * Tt + t) * Hh + d;
                    hs[oi] = hn;
                    cs[oi] = cn;
                }
            }
        }
        if (tid < 256 && t + 1 < Tt) {  // write x_{t+1}
            int r = tid >> 4, c = (tid & 15) * 8;
            s16x8 v;
            v[0] = (short)f2b(xp0.x); v[1] = (short)f2b(xp0.y);
            v[2] = (short)f2b(xp0.z); v[3] = (short)f2b(xp0.w);
            v[4] = (short)f2b(xp1.x); v[5] = (short)f2b(xp1.y);
            v[6] = (short)f2b(xp1.z); v[7] = (short)f2b(xp1.w);
            *(s16x8*)&z_bf[r][c] = v;
        }
        // refill A1 ring (kc 0..4) for next step — weights only, no dependency
        #pragma unroll
        for (int kc = 0; kc < 5; ++kc) {
            bufA[kc][0] = W8[CH_A1 + (w * A1_NK + kc) * 64 + l];
            bufA[kc][1] = W8[CH_A1 + ((8 + w) * A1_NK + kc) * 64 + l];
        }
        __syncthreads();  // ---- state for t+1 ready ----
    }
}

extern "C" void kernel_launch(void* const* d_in, const int* in_sizes, int n_in,
                              void* d_out, int out_size, void* d_ws, size_t ws_size,
                              hipStream_t stream) {
    const float* X   = (const float*)d_in[0];
    const float* a1W = (const float*)d_in[1];
    const float* a1b = (const float*)d_in[2];
    const float* a2W = (const float*)d_in[3];
    const float* a2b = (const float*)d_in[4];
    const float* Wih = (const float*)d_in[5];
    const float* Whh = (const float*)d_in[6];
    const float* bih = (const float*)d_in[7];
    const float* bhh = (const float*)d_in[8];
    ushort_t* ws = (ushort_t*)d_ws;

    hipLaunchKernelGGL(conv_kernel, dim3(CH_TOTAL / 256), dim3(256), 0, stream,
                       a1W, a2W, Wih, Whh, ws);
    hipLaunchKernelGGL(lstm_mfma, dim3(32), dim3(512), 0, stream,
                       X, a1b, a2b, bih, bhh, ws, (float*)d_out);
}